// Round 3
// baseline (223.106 us; speedup 1.0000x reference)
//
#include <hip/hip_runtime.h>

// Problem: B=8192, L=128, O=512, K=8, H=20
#define B_TOT 8192
#define O_DIM 512
#define L_DIM 128
#define K_DIM 8
#define H_DIM 20

// Tiling: one o per wave; each wave covers RBS*64 = 128 b.
// Block = 4 waves x (TO/NW=4 o-iterations) => 16 o x 128 b per block.
// No LDS at all: x (4 MB) and noise lines are L1/L2-resident gathers;
// weights ride the scalar path (wave-uniform o => s_load into SGPRs).
#define TO  16
#define TBB 128
#define RBS 2
#define NW  4
#define NTH 256

// tanh(x) = 1 - 2/(1+exp(2x)); saturates correctly at +/-inf.
__device__ __forceinline__ float fast_tanh(float x) {
    float e = __builtin_amdgcn_exp2f(x * 2.885390081777927f); // 2*log2(e)
    float r = __builtin_amdgcn_rcpf(1.0f + e);
    return 1.0f - 2.0f * r;
}

__global__ __launch_bounds__(NTH, 4) void medil_fused(
    const float* __restrict__ x, const float* __restrict__ noise,
    const int* __restrict__ cause_idx,
    const float* __restrict__ W1, const float* __restrict__ b1,
    const float* __restrict__ W2, const float* __restrict__ b2,
    const float* __restrict__ W3, const float* __restrict__ b3,
    float* __restrict__ out)
{
    const int tid  = threadIdx.x;
    const int lane = tid & 63;
    const int wv   = tid >> 6;
    const int o0 = (blockIdx.x & 31) * TO;        // 32 o-groups
    const int b0 = (blockIdx.x >> 5) * TBB;       // 64 b-tiles

    int brow[RBS];
    #pragma unroll
    for (int r = 0; r < RBS; ++r) brow[r] = b0 + r * 64 + lane;

    #pragma unroll 1   // keep rolled: bounds VGPRs; 4 waves/SIMD hide per-iter s_load latency
    for (int it = 0; it < TO / NW; ++it) {
        // wave-uniform o => W/b/idx accesses become scalar (s_load) reads
        const int ol = __builtin_amdgcn_readfirstlane(wv * (TO / NW) + it);
        const int o  = o0 + ol;

        const float* w1p = W1 + (size_t)o * (K_DIM + 1) * H_DIM;
        const float* b1p = b1 + (size_t)o * H_DIM;
        const float* w2p = W2 + (size_t)o * H_DIM * H_DIM;
        const float* b2p = b2 + (size_t)o * H_DIM;
        const float* w3p = W3 + (size_t)o * H_DIM;
        const int*   cip = cause_idx + (size_t)o * K_DIM;

        // ---- gathers first so VMEM latency overlaps the math body ----
        float xi[RBS][K_DIM];
        #pragma unroll
        for (int k = 0; k < K_DIM; ++k) {
            const int col = cip[k];
            #pragma unroll
            for (int r = 0; r < RBS; ++r)
                xi[r][k] = x[(size_t)brow[r] * L_DIM + col];
        }
        float inp0[RBS];
        #pragma unroll
        for (int r = 0; r < RBS; ++r)
            inp0[r] = noise[(size_t)brow[r] * O_DIM + o];   // 64B line = this block's 16 o's -> L1 hit

        // ---- layer 1: a1 = tanh(inp @ W1 + b1) ----
        float a1[RBS][H_DIM];
        #pragma unroll
        for (int h = 0; h < H_DIM; ++h) {
            const float w = w1p[h], bb = b1p[h];
            #pragma unroll
            for (int r = 0; r < RBS; ++r) a1[r][h] = fmaf(inp0[r], w, bb);
        }
        #pragma unroll
        for (int k = 0; k < K_DIM; ++k)
            #pragma unroll
            for (int h = 0; h < H_DIM; ++h) {
                const float w = w1p[(k + 1) * H_DIM + h];
                #pragma unroll
                for (int r = 0; r < RBS; ++r) a1[r][h] = fmaf(xi[r][k], w, a1[r][h]);
            }
        #pragma unroll
        for (int h = 0; h < H_DIM; ++h)
            #pragma unroll
            for (int r = 0; r < RBS; ++r) a1[r][h] = fast_tanh(a1[r][h]);

        // ---- layer 2: a2 = tanh(a1 @ W2 + b2) ----
        float a2[RBS][H_DIM];
        #pragma unroll
        for (int g = 0; g < H_DIM; ++g) {
            const float bb = b2p[g];
            #pragma unroll
            for (int r = 0; r < RBS; ++r) a2[r][g] = bb;
        }
        #pragma unroll
        for (int h = 0; h < H_DIM; ++h)
            #pragma unroll
            for (int g = 0; g < H_DIM; ++g) {
                const float w = w2p[h * H_DIM + g];
                #pragma unroll
                for (int r = 0; r < RBS; ++r) a2[r][g] = fmaf(a1[r][h], w, a2[r][g]);
            }
        #pragma unroll
        for (int g = 0; g < H_DIM; ++g)
            #pragma unroll
            for (int r = 0; r < RBS; ++r) a2[r][g] = fast_tanh(a2[r][g]);

        // ---- layer 3 + store ----
        const float b3v = b3[o];
        float res[RBS];
        #pragma unroll
        for (int r = 0; r < RBS; ++r) res[r] = b3v;
        #pragma unroll
        for (int h = 0; h < H_DIM; ++h) {
            const float w = w3p[h];
            #pragma unroll
            for (int r = 0; r < RBS; ++r) res[r] = fmaf(a2[r][h], w, res[r]);
        }
        #pragma unroll
        for (int r = 0; r < RBS; ++r)
            out[(size_t)brow[r] * O_DIM + o] = res[r];   // L2 write-combines across the block's o's
    }
}

extern "C" void kernel_launch(void* const* d_in, const int* in_sizes, int n_in,
                              void* d_out, int out_size, void* d_ws, size_t ws_size,
                              hipStream_t stream) {
    const float* x         = (const float*)d_in[0];
    const float* noise     = (const float*)d_in[1];
    const int*   cause_idx = (const int*)d_in[2];
    const float* W1        = (const float*)d_in[3];
    const float* b1        = (const float*)d_in[4];
    const float* W2        = (const float*)d_in[5];
    const float* b2        = (const float*)d_in[6];
    const float* W3        = (const float*)d_in[7];
    const float* b3        = (const float*)d_in[8];
    float* out = (float*)d_out;

    dim3 grid((B_TOT / TBB) * (O_DIM / TO));   // 64 * 32 = 2048 blocks
    dim3 block(NTH);
    hipLaunchKernelGGL(medil_fused, grid, block, 0, stream,
                       x, noise, cause_idx, W1, b1, W2, b2, W3, b3, out);
}

// Round 4
// 197.265 us; speedup vs baseline: 1.1310x; 1.1310x over previous
//
#include <hip/hip_runtime.h>

// Problem: B=8192, L=128, O=512, K=8, H=20
#define B_TOT 8192
#define O_DIM 512
#define L_DIM 128
#define K_DIM 8
#define H_DIM 20

// Tiling: one o per wave; each wave covers RBS*64 = 128 b.
// Block = 4 waves x (TO/NW=4 o-iterations) => 16 o x 128 b per block.
// x tile in LDS, transposed [col][b] with XOR swizzle (conflict-free both ways).
// Weights ride the scalar path (wave-uniform o => s_load into SGPRs).
#define TO  16
#define TBB 128
#define RBS 2
#define NW  4
#define NTH 256

// tanh(x) = 1 - 2/(1+exp(2x)); saturates correctly at +/-inf.
__device__ __forceinline__ float fast_tanh(float x) {
    float e = __builtin_amdgcn_exp2f(x * 2.885390081777927f); // 2*log2(e)
    float r = __builtin_amdgcn_rcpf(1.0f + e);
    return 1.0f - 2.0f * r;
}

__global__ __launch_bounds__(NTH, 2) void medil_fused(
    const float* __restrict__ x, const float* __restrict__ noise,
    const int* __restrict__ cause_idx,
    const float* __restrict__ W1, const float* __restrict__ b1,
    const float* __restrict__ W2, const float* __restrict__ b2,
    const float* __restrict__ W3, const float* __restrict__ b3,
    float* __restrict__ out)
{
    // xT[col][b] at float index col*128 + (b ^ ((col>>2)&31)).
    // Writes: lanes vary col at fixed b -> (b^c4) covers all 32 banks, 2-way, free.
    // Reads: col uniform, lanes vary b -> XOR permutes banks, 2-way, free.
    __shared__ float xT[L_DIM * TBB];   // exactly 64 KB -> 2 blocks/CU

    const int tid  = threadIdx.x;
    const int lane = tid & 63;
    const int wv   = tid >> 6;
    const int o0 = (blockIdx.x & 31) * TO;        // o-group = fast index (x reuse in L2/LLC)
    const int b0 = (blockIdx.x >> 5) * TBB;       // 64 b-tiles

    // ---- stage x tile: coalesced float4 global reads, swizzled scalar LDS writes ----
    {
        const float4* xg = (const float4*)(x + (size_t)b0 * L_DIM);
        #pragma unroll
        for (int i = 0; i < 16; ++i) {
            int idx  = tid + NTH * i;             // 0..4095
            int rloc = idx >> 5;                  // local b row 0..127
            int c4   = idx & 31;                  // float4 column 0..31
            float4 v = xg[idx];
            int base = (4 * c4) * TBB + (rloc ^ c4);
            xT[base + 0 * TBB] = v.x;
            xT[base + 1 * TBB] = v.y;
            xT[base + 2 * TBB] = v.z;
            xT[base + 3 * TBB] = v.w;
        }
    }
    __syncthreads();

    #pragma unroll 1   // keep rolled: bounds VGPRs
    for (int it = 0; it < TO / NW; ++it) {
        // wave-uniform o => W/b/idx accesses become scalar (s_load) reads
        const int ol = __builtin_amdgcn_readfirstlane(wv * (TO / NW) + it);
        const int o  = o0 + ol;

        const float* w1p = W1 + (size_t)o * (K_DIM + 1) * H_DIM;
        const float* b1p = b1 + (size_t)o * H_DIM;
        const float* w2p = W2 + (size_t)o * H_DIM * H_DIM;
        const float* b2p = b2 + (size_t)o * H_DIM;
        const float* w3p = W3 + (size_t)o * H_DIM;
        const int*   cip = cause_idx + (size_t)o * K_DIM;

        // ---- gathers from LDS (conflict-free) + noise (L1-resident line) ----
        float xi[RBS][K_DIM];
        #pragma unroll
        for (int k = 0; k < K_DIM; ++k) {
            const int col = cip[k];
            const int sw  = (col >> 2) & 31;
            #pragma unroll
            for (int r = 0; r < RBS; ++r)
                xi[r][k] = xT[col * TBB + ((lane + 64 * r) ^ sw)];
        }
        float inp0[RBS];
        #pragma unroll
        for (int r = 0; r < RBS; ++r)
            inp0[r] = noise[(size_t)(b0 + 64 * r + lane) * O_DIM + o];

        // ---- layer 1: a1 = tanh(inp @ W1 + b1) ----
        float a1[RBS][H_DIM];
        #pragma unroll
        for (int h = 0; h < H_DIM; ++h) {
            const float w = w1p[h], bb = b1p[h];
            #pragma unroll
            for (int r = 0; r < RBS; ++r) a1[r][h] = fmaf(inp0[r], w, bb);
        }
        #pragma unroll
        for (int k = 0; k < K_DIM; ++k)
            #pragma unroll
            for (int h = 0; h < H_DIM; ++h) {
                const float w = w1p[(k + 1) * H_DIM + h];
                #pragma unroll
                for (int r = 0; r < RBS; ++r) a1[r][h] = fmaf(xi[r][k], w, a1[r][h]);
            }
        #pragma unroll
        for (int h = 0; h < H_DIM; ++h)
            #pragma unroll
            for (int r = 0; r < RBS; ++r) a1[r][h] = fast_tanh(a1[r][h]);

        // ---- layer 2: a2 = tanh(a1 @ W2 + b2) ----
        float a2[RBS][H_DIM];
        #pragma unroll
        for (int g = 0; g < H_DIM; ++g) {
            const float bb = b2p[g];
            #pragma unroll
            for (int r = 0; r < RBS; ++r) a2[r][g] = bb;
        }
        #pragma unroll
        for (int h = 0; h < H_DIM; ++h)
            #pragma unroll
            for (int g = 0; g < H_DIM; ++g) {
                const float w = w2p[h * H_DIM + g];
                #pragma unroll
                for (int r = 0; r < RBS; ++r) a2[r][g] = fmaf(a1[r][h], w, a2[r][g]);
            }
        #pragma unroll
        for (int g = 0; g < H_DIM; ++g)
            #pragma unroll
            for (int r = 0; r < RBS; ++r) a2[r][g] = fast_tanh(a2[r][g]);

        // ---- layer 3 + store ----
        const float b3v = b3[o];
        float res[RBS];
        #pragma unroll
        for (int r = 0; r < RBS; ++r) res[r] = b3v;
        #pragma unroll
        for (int h = 0; h < H_DIM; ++h) {
            const float w = w3p[h];
            #pragma unroll
            for (int r = 0; r < RBS; ++r) res[r] = fmaf(a2[r][h], w, res[r]);
        }
        #pragma unroll
        for (int r = 0; r < RBS; ++r)
            out[(size_t)(b0 + 64 * r + lane) * O_DIM + o] = res[r];
    }
}

extern "C" void kernel_launch(void* const* d_in, const int* in_sizes, int n_in,
                              void* d_out, int out_size, void* d_ws, size_t ws_size,
                              hipStream_t stream) {
    const float* x         = (const float*)d_in[0];
    const float* noise     = (const float*)d_in[1];
    const int*   cause_idx = (const int*)d_in[2];
    const float* W1        = (const float*)d_in[3];
    const float* b1        = (const float*)d_in[4];
    const float* W2        = (const float*)d_in[5];
    const float* b2        = (const float*)d_in[6];
    const float* W3        = (const float*)d_in[7];
    const float* b3        = (const float*)d_in[8];
    float* out = (float*)d_out;

    dim3 grid((B_TOT / TBB) * (O_DIM / TO));   // 64 * 32 = 2048 blocks
    dim3 block(NTH);
    hipLaunchKernelGGL(medil_fused, grid, block, 0, stream,
                       x, noise, cause_idx, W1, b1, W2, b2, W3, b3, out);
}